// Round 9
// baseline (276.524 us; speedup 1.0000x reference)
//
#include <hip/hip_runtime.h>
#include <hip/hip_bf16.h>
#include <math.h>

#define N_NODES 50000
#define N_EDGES 1600000
#define IN_DIM  128
#define OUT_DIM 32
#define N_HEADS 4
#define WH_DIM  (N_HEADS * OUT_DIM)   // 128
#define CAP     128                   // per-node LDS edge cache (max deg ~58)
#define NPASS   4                     // dst-windows
#define WIN     (N_NODES / NPASS)     // 12500
#define NCH2    32                    // chunks per window
#define SEGCAP  410000                // per-window capacity
#define UNROLL  16                    // edges per thread in cvt blocks
#define EPB     (256 * UNROLL)        // 4096 edges per cvt block
#define NB_CVT  391                   // ceil(1600000/4096)
#define NB_WH   782                   // ceil(50000/64)
#define NB_SORT (NCH2 * NPASS)        // 128 sort blocks (co-resident: cap 512)
#define NB_P2   49                    // ceil(50000/1024) scan blocks
#define NB_PREP 16

typedef __attribute__((ext_vector_type(8))) short short8;     // 8 bf16
typedef __attribute__((ext_vector_type(4))) float floatx4;    // MFMA acc

__device__ __forceinline__ short f2bf(float v) {
    __hip_bfloat16 b = __float2bfloat16(v);
    return *reinterpret_cast<short*>(&b);
}
__device__ __forceinline__ float lrelu(float v) {
    return v > 0.0f ? v : 0.2f * v;
}

// ---------------------------------------------------------------------------
// edge_index may arrive as int32 or int64 (reference dtype).
// ---------------------------------------------------------------------------
__device__ __forceinline__ void load_edge(const void* eidx, int is32, int e,
                                          int& s, int& d) {
    if (is32) {
        const int2 v = ((const int2*)eidx)[e];
        s = v.x; d = v.y;
    } else {
        const longlong2 v = ((const longlong2*)eidx)[e];
        s = (int)v.x; d = (int)v.y;
    }
}

// ---------------------------------------------------------------------------
// Grid barrier for k_sort: all NB_SORT blocks guaranteed co-resident
// (1024-thr blocks -> 2/CU x 256 CUs = 512 slots >= 128). threadfence
// (agent-scope fence: L2 writeback on release, invalidate on acquire)
// brackets the atomic counter -> non-atomic cross-block data is safe.
// Distinct counter per phase; counters re-zeroed each run by k_prep0.
// ---------------------------------------------------------------------------
__device__ __forceinline__ void gbar(int* bar, int idx) {
    __syncthreads();
    if (threadIdx.x == 0) {
        __threadfence();
        atomicAdd(&bar[idx], 1);
        while (atomicAdd(&bar[idx], 0) < NB_SORT) {}
        __threadfence();
    }
    __syncthreads();
}

// ---------------------------------------------------------------------------
// k_prep0 (16 blocks): zero counters (block 0), compute U (block 0), build
// swizzled bf16 B panel split 16 ways (removes single-block latency serial).
// ---------------------------------------------------------------------------
__global__ __launch_bounds__(256) void k_prep0(
        const float* __restrict__ weight, const float* __restrict__ attn,
        short* __restrict__ bsw_pre, int* __restrict__ win_cnt,
        int* __restrict__ bar) {
    __shared__ float ubuf[128 * 8];            // 4 KB
    const int t = threadIdx.x;
    const int b = blockIdx.x;
    // ---- main panel slice: 1024 entries per block
    for (int f = b * 1024 + t; f < (b + 1) * 1024; f += 256) {
        int k = f >> 7, c = f & 127;
        float w = weight[(c >> 5) * (IN_DIM * OUT_DIM) + k * OUT_DIM + (c & 31)];
        int kc = k >> 5, quad = (k >> 3) & 3, j = k & 7;
        bsw_pre[((kc * 9 + (c >> 4)) * 64 + quad * 16 + (c & 15)) * 8 + j] =
            f2bf(w);
    }
    if (b != 0) return;
    // ---- block 0: zero counters, U, extension cols
    if (t < NPASS) win_cnt[t] = 0;
    if (t < 8) bar[t] = 0;
    {
        int c = t & 7, k0 = t >> 3;            // k0 in [0,32)
        int h = c & 3;
        const float* ap = attn + h * 64 + (c >> 2) * 32;
        for (int k = k0; k < 128; k += 32) {
            const float* wp = weight + h * (IN_DIM * OUT_DIM) + k * OUT_DIM;
            float u = 0.f;
#pragma unroll
            for (int o = 0; o < 32; o += 4) {
                float4 wv = *(const float4*)(wp + o);
                float4 av = *(const float4*)(ap + o);
                u += wv.x * av.x + wv.y * av.y + wv.z * av.z + wv.w * av.w;
            }
            ubuf[k * 8 + c] = u;
        }
    }
    __syncthreads();
    for (int f = t; f < 128 * 16; f += 256) {
        int k = f >> 4, c = f & 15;
        float w = (c < 8) ? ubuf[k * 8 + c] : 0.f;
        int kc = k >> 5, quad = (k >> 3) & 3, j = k & 7;
        bsw_pre[((kc * 9 + 8) * 64 + quad * 16 + c) * 8 + j] = f2bf(w);
    }
}

// ---------------------------------------------------------------------------
// k_cvtwh: FUSED edge-binning + Wh GEMM (independent work, one launch).
// Blocks [0,NB_CVT): bin edges into 4 dst-window segments, PACKED as
//   p = s | ((d - w*WIN) << 17). Ballot ranks, ONE atomicAdd/window/block.
// Blocks [NB_CVT,..): 64 nodes x 144 cols MFMA GEMM from bsw_pre.
// ---------------------------------------------------------------------------
union CvtWhSmem {
    struct {
        int s_is32;
        int wcnt[NPASS][UNROLL][4];            // [win][iter][wave]
        int pb[NPASS][UNROLL][4];              // block-relative bases
        int bw[NPASS];                         // per-window block base
    } c;
    struct {
        short xsw[4 * 4 * 64 * 8];             // 16 KB [wg][kc][lane][j]
        short bsw[4 * 9 * 64 * 8];             // 36 KB [kc][cg][lane][j]
    } w;
};

__global__ __launch_bounds__(256) void k_cvtwh(
        const void* __restrict__ eidx, const float* __restrict__ x,
        const short* __restrict__ bsw_pre,
        int* __restrict__ win_cnt, int* __restrict__ win_sd,
        __hip_bfloat16* __restrict__ Wh16, float* __restrict__ sb16) {
    __shared__ CvtWhSmem sm;
    const int t = threadIdx.x;

    if (blockIdx.x < NB_CVT) {
        // ================= cvt branch =================
        const int wv = t >> 6, lane = t & 63;
        if (t < 64) {
            int hi = ((const int*)eidx)[2 * (t * 25000) + 1];
            unsigned long long b = __ballot(hi != 0);
            if (t == 0) sm.c.s_is32 = (b != 0ULL) ? 1 : 0;
        }
        __syncthreads();
        const int is32 = sm.c.s_is32;
        const int e0 = blockIdx.x * EPB;
        int sg[UNROLL], dg[UNROLL];
#pragma unroll
        for (int i = 0; i < UNROLL; ++i) {
            const int e = e0 + i * 256 + t;
            int s = 0, d = -1;
            if (e < N_EDGES) load_edge(eidx, is32, e, s, d);
            sg[i] = s; dg[i] = d;
            const int w = (d >= 0) ? (d / WIN) : -1;
            const unsigned long long m0 = __ballot(w == 0);
            const unsigned long long m1 = __ballot(w == 1);
            const unsigned long long m2 = __ballot(w == 2);
            const unsigned long long m3 = __ballot(w == 3);
            if (lane == 0) {
                sm.c.wcnt[0][i][wv] = __popcll(m0);
                sm.c.wcnt[1][i][wv] = __popcll(m1);
                sm.c.wcnt[2][i][wv] = __popcll(m2);
                sm.c.wcnt[3][i][wv] = __popcll(m3);
            }
        }
        __syncthreads();
        if (t < NPASS) {
            int run = 0;
            for (int i = 0; i < UNROLL; ++i)
                for (int v = 0; v < 4; ++v) {
                    sm.c.pb[t][i][v] = run;
                    run += sm.c.wcnt[t][i][v];
                }
            sm.c.bw[t] = atomicAdd(&win_cnt[t], run);
        }
        __syncthreads();
        const unsigned long long mlt = (1ULL << lane) - 1ULL;
#pragma unroll
        for (int i = 0; i < UNROLL; ++i) {
            const int d = dg[i];
            const int w = (d >= 0) ? (d / WIN) : -1;
            const unsigned long long m0 = __ballot(w == 0);
            const unsigned long long m1 = __ballot(w == 1);
            const unsigned long long m2 = __ballot(w == 2);
            const unsigned long long m3 = __ballot(w == 3);
            if (w >= 0) {
                const unsigned long long mw = (w == 0) ? m0 : (w == 1) ? m1
                                            : (w == 2) ? m2 : m3;
                const int rank = __popcll(mw & mlt);
                const int p = sm.c.bw[w] + sm.c.pb[w][i][wv] + rank;
                if (p < SEGCAP)
                    win_sd[w * SEGCAP + p] = sg[i] | ((d - w * WIN) << 17);
            }
        }
    } else {
        // ================= wh branch =================
        const int nb = (blockIdx.x - NB_CVT) * 64;
        for (int f = t; f < 4 * 9 * 64; f += 256)
            *(short8*)&sm.w.bsw[f * 8] = *(const short8*)&bsw_pre[f * 8];
        for (int f = t; f < 64 * 32; f += 256) {
            int n = f >> 5, k = (f & 31) * 4;
            int ng = nb + n; if (ng > N_NODES - 1) ng = N_NODES - 1;
            float4 v = *(const float4*)(x + (size_t)ng * IN_DIM + k);
            int wg = n >> 4, m = n & 15, kc = k >> 5, quad = (k >> 3) & 3,
                j = k & 7;
            short4 sv = make_short4(f2bf(v.x), f2bf(v.y), f2bf(v.z), f2bf(v.w));
            *(short4*)&sm.w.xsw[(((wg * 4 + kc) * 64) + quad * 16 + m) * 8 + j]
                = sv;
        }
        __syncthreads();
        const int wg = t >> 6, lane = t & 63;
        floatx4 acc[9];
#pragma unroll
        for (int i = 0; i < 9; ++i) acc[i] = (floatx4){0.f, 0.f, 0.f, 0.f};
#pragma unroll
        for (int kc = 0; kc < 4; ++kc) {
            short8 a = *(short8*)&sm.w.xsw[((wg * 4 + kc) * 64 + lane) * 8];
#pragma unroll
            for (int cg = 0; cg < 9; ++cg) {
                short8 b = *(short8*)&sm.w.bsw[((kc * 9 + cg) * 64 + lane) * 8];
                acc[cg] = __builtin_amdgcn_mfma_f32_16x16x32_bf16(a, b, acc[cg],
                                                                  0, 0, 0);
            }
        }
        const int col = lane & 15, quad = lane >> 4;
#pragma unroll
        for (int r = 0; r < 4; ++r) {
            int n = nb + wg * 16 + quad * 4 + r;
            if (n >= N_NODES) continue;
#pragma unroll
            for (int cg = 0; cg < 8; ++cg)
                Wh16[(size_t)n * WH_DIM + cg * 16 + col] =
                    __float2bfloat16(acc[cg][r]);
            if (col < 8) sb16[(size_t)n * 16 + col] = acc[8][r];
        }
    }
}

// ---------------------------------------------------------------------------
// k_sort: FUSED hist + scan + base + scatter (was 3 launches).
// 128 blocks x 1024; grid barriers via gbar (co-residency guaranteed).
// P1: per-(chunk,window) LDS histogram -> hist.
// P2: blocks 0..48 scan 1024 nodes each (LDS Hillis-Steele), publish block
//     sums, cross-block prefix, emit noff + in-place base conversion.
// P3: scatter via LDS atomics on bases (window csr region L2-resident).
// ---------------------------------------------------------------------------
__global__ __launch_bounds__(1024) void k_sort(
        const int* __restrict__ win_cnt, const int* __restrict__ win_sd,
        int* __restrict__ hist, int* __restrict__ bsum2,
        int* __restrict__ noff, int* __restrict__ csr, int* __restrict__ bar) {
    __shared__ int lds[WIN];                   // 50 KB, reused per phase
    __shared__ int xb;
    const int bid = blockIdx.x;
    const int t = threadIdx.x;
    const int c = bid & (NCH2 - 1), w = bid >> 5;
    // ---- P1: histogram
    for (int i = t; i < WIN; i += 1024) lds[i] = 0;
    __syncthreads();
    const int cw = win_cnt[w];
    const int ce = (cw + NCH2 - 1) / NCH2;
    const int lo = c * ce, hi = min(lo + ce, cw);
    for (int i = lo + t; i < hi; i += 1024) {
        unsigned u = ((unsigned)win_sd[w * SEGCAP + i]) >> 17;
        if (u < WIN) atomicAdd(&lds[u], 1);
    }
    __syncthreads();
    for (int i = t; i < WIN; i += 1024)
        hist[(w * NCH2 + c) * WIN + i] = lds[i];
    gbar(bar, 0);
    // ---- P2a: block-local scan over 1024 nodes (blocks 0..NB_P2-1)
    int myex = 0, vdeg = 0;
    if (bid < NB_P2) {
        const int i = bid * 1024 + t;
        int v = 0;
        if (i < N_NODES) {
            const int w2 = i / WIN, bin = i % WIN;
            for (int cc = 0; cc < NCH2; ++cc)
                v += hist[(w2 * NCH2 + cc) * WIN + bin];
        }
        vdeg = v;
        lds[t] = v;
        __syncthreads();
        for (int d = 1; d < 1024; d <<= 1) {
            int u = (t >= d) ? lds[t - d] : 0;
            __syncthreads();
            lds[t] += u;
            __syncthreads();
        }
        myex = lds[t] - vdeg;
        if (t == 1023) bsum2[bid] = lds[1023];
    }
    gbar(bar, 1);
    // ---- P2b: cross-block prefix + noff + base conversion
    if (bid < NB_P2) {
        if (t < NB_P2) lds[t] = bsum2[t];
        __syncthreads();
        if (t == 0) {
            int e = 0;
            for (int j = 0; j < bid; ++j) e += lds[j];
            xb = e;
        }
        __syncthreads();
        const int exb = xb;
        if (bid == 0 && t == 0) noff[N_NODES] = N_EDGES;
        const int i = bid * 1024 + t;
        if (i < N_NODES) {
            int run = myex + exb;
            noff[i] = run;
            const int w2 = i / WIN, bin = i % WIN;
            for (int cc = 0; cc < NCH2; ++cc) {
                const int idx = (w2 * NCH2 + cc) * WIN + bin;
                int t0 = hist[idx];
                hist[idx] = run;
                run += t0;
            }
        }
    }
    gbar(bar, 2);
    // ---- P3: scatter
    for (int i = t; i < WIN; i += 1024)
        lds[i] = hist[(w * NCH2 + c) * WIN + i];
    __syncthreads();
    for (int i = lo + t; i < hi; i += 1024) {
        const int pk = win_sd[w * SEGCAP + i];
        const unsigned u = ((unsigned)pk) >> 17;
        if (u < WIN) {
            int p = atomicAdd(&lds[u], 1);
            csr[p] = pk & 0x1FFFF;
        }
    }
}

// ---------------------------------------------------------------------------
// One wave per dst node. No max pass (softmax shift-invariant; |e| small).
// sb16 row: [0..3]=s_src, [4..7]=s_dst, [8..11]=inv (written here), 64 B.
// Phase D: esl = t>>4 picks 1 of 4 edges, dsl = t&15 picks an 8-dim slice;
// 16-edge unroll -> 4 independent gathers in flight per wave.
// ---------------------------------------------------------------------------
__global__ __launch_bounds__(256) void k_node(
        const int* __restrict__ noff,
        const int* __restrict__ csr, float* __restrict__ sb16,
        const __hip_bfloat16* __restrict__ Wh16,
        float* __restrict__ out_h) {
    __shared__ int    sbuf[4][CAP];
    __shared__ float4 e4b[4][CAP];                      // exp(e) values
    const int wv = threadIdx.x >> 6;
    const int t  = threadIdx.x & 63;
    const int n  = blockIdx.x * 4 + wv;
    const int beg = noff[n];
    const int end = noff[n + 1];
    const int deg = end - beg;

    const float4 sd = *(const float4*)(sb16 + (size_t)n * 16 + 4);

    // Phase A: ex = exp(lrelu(s_src[src] + s_dst[n])); cache; running sum
    float4 sum = {0.f, 0.f, 0.f, 0.f};
    for (int l = t; l < deg; l += 64) {
        int s = csr[beg + l];
        float4 ss = *(const float4*)(sb16 + (size_t)s * 16);
        float4 ex;
        ex.x = __expf(lrelu(ss.x + sd.x));
        ex.y = __expf(lrelu(ss.y + sd.y));
        ex.z = __expf(lrelu(ss.z + sd.z));
        ex.w = __expf(lrelu(ss.w + sd.w));
        if (l < CAP) { sbuf[wv][l] = s; e4b[wv][l] = ex; }
        sum.x += ex.x; sum.y += ex.y; sum.z += ex.z; sum.w += ex.w;
    }
#pragma unroll
    for (int o = 32; o; o >>= 1) {
        sum.x += __shfl_xor(sum.x, o);
        sum.y += __shfl_xor(sum.y, o);
        sum.z += __shfl_xor(sum.z, o);
        sum.w += __shfl_xor(sum.w, o);
    }
    float4 inv;
    inv.x = 1.0f / (sum.x + 1e-9f); inv.y = 1.0f / (sum.y + 1e-9f);
    inv.z = 1.0f / (sum.z + 1e-9f); inv.w = 1.0f / (sum.w + 1e-9f);
    if (t == 0) *(float4*)(sb16 + (size_t)n * 16 + 8) = inv;

    // Phase D
    const int esl = t >> 4;
    const int dsl = t & 15;
    const int h   = dsl >> 2;
    const float invh = (h == 0) ? inv.x : (h == 1) ? inv.y
                     : (h == 2) ? inv.z : inv.w;
    const float sdh  = (h == 0) ? sd.x : (h == 1) ? sd.y
                     : (h == 2) ? sd.z : sd.w;
    float acc0 = 0.f, acc1 = 0.f, acc2 = 0.f, acc3 = 0.f;
    float acc4 = 0.f, acc5 = 0.f, acc6 = 0.f, acc7 = 0.f;
    if (deg <= CAP) {
        const int sPad = sbuf[wv][0];
        for (int jb = 0; jb < deg; jb += 16) {
            int   sg[4];
            float ag[4];
#pragma unroll
            for (int g = 0; g < 4; ++g) {
                const int idx = jb + g * 4 + esl;
                sg[g] = sPad;
                ag[g] = 0.f;
                if (idx < deg) {
                    sg[g] = sbuf[wv][idx];
                    ag[g] = ((const float*)&e4b[wv][idx])[h];
                }
            }
            uint4 w0 = *(const uint4*)(Wh16 + (size_t)sg[0] * WH_DIM + dsl * 8);
            uint4 w1 = *(const uint4*)(Wh16 + (size_t)sg[1] * WH_DIM + dsl * 8);
            uint4 w2 = *(const uint4*)(Wh16 + (size_t)sg[2] * WH_DIM + dsl * 8);
            uint4 w3 = *(const uint4*)(Wh16 + (size_t)sg[3] * WH_DIM + dsl * 8);
#define ACC8(W, A)                                                            \
            acc0 += (A) * __uint_as_float((W).x << 16);                       \
            acc1 += (A) * __uint_as_float((W).x & 0xffff0000u);               \
            acc2 += (A) * __uint_as_float((W).y << 16);                       \
            acc3 += (A) * __uint_as_float((W).y & 0xffff0000u);               \
            acc4 += (A) * __uint_as_float((W).z << 16);                       \
            acc5 += (A) * __uint_as_float((W).z & 0xffff0000u);               \
            acc6 += (A) * __uint_as_float((W).w << 16);                       \
            acc7 += (A) * __uint_as_float((W).w & 0xffff0000u)
            ACC8(w0, ag[0]);
            ACC8(w1, ag[1]);
            ACC8(w2, ag[2]);
            ACC8(w3, ag[3]);
#undef ACC8
        }
    } else {
        for (int jb = 0; jb < deg; jb += 4) {
            const int idx = jb + esl;
            float a = 0.f;
            int s = sbuf[wv][0];
            if (idx < deg) {
                if (idx < CAP) {
                    s = sbuf[wv][idx];
                    a = ((const float*)&e4b[wv][idx])[h];
                } else {
                    s = csr[beg + idx];
                    a = __expf(lrelu(sb16[(size_t)s * 16 + h] + sdh));
                }
            }
            const uint4 w = *(const uint4*)(Wh16 + (size_t)s * WH_DIM + dsl * 8);
            acc0 += a * __uint_as_float(w.x << 16);
            acc1 += a * __uint_as_float(w.x & 0xffff0000u);
            acc2 += a * __uint_as_float(w.y << 16);
            acc3 += a * __uint_as_float(w.y & 0xffff0000u);
            acc4 += a * __uint_as_float(w.z << 16);
            acc5 += a * __uint_as_float(w.z & 0xffff0000u);
            acc6 += a * __uint_as_float(w.w << 16);
            acc7 += a * __uint_as_float(w.w & 0xffff0000u);
        }
    }
    acc0 += __shfl_xor(acc0, 16); acc0 += __shfl_xor(acc0, 32);
    acc1 += __shfl_xor(acc1, 16); acc1 += __shfl_xor(acc1, 32);
    acc2 += __shfl_xor(acc2, 16); acc2 += __shfl_xor(acc2, 32);
    acc3 += __shfl_xor(acc3, 16); acc3 += __shfl_xor(acc3, 32);
    acc4 += __shfl_xor(acc4, 16); acc4 += __shfl_xor(acc4, 32);
    acc5 += __shfl_xor(acc5, 16); acc5 += __shfl_xor(acc5, 32);
    acc6 += __shfl_xor(acc6, 16); acc6 += __shfl_xor(acc6, 32);
    acc7 += __shfl_xor(acc7, 16); acc7 += __shfl_xor(acc7, 32);
    if (t < 16) {
        float* op = out_h + (size_t)n * WH_DIM + dsl * 8;
        float4 o0 = {acc0 * invh, acc1 * invh, acc2 * invh, acc3 * invh};
        float4 o1 = {acc4 * invh, acc5 * invh, acc6 * invh, acc7 * invh};
        *(float4*)op = o0;
        *(float4*)(op + 4) = o1;
    }
}

// ---------------------------------------------------------------------------
// Edge-parallel alpha: reads eidx directly (L3-resident); dst-side gather
// (sd+inv) hits one 64 B line per edge; coalesced float4 write.
// ---------------------------------------------------------------------------
__global__ __launch_bounds__(256) void k_alpha(
        const void* __restrict__ eidx,
        const float* __restrict__ sb16, float* __restrict__ ebuf) {
    __shared__ int s_is32;
    const int t = threadIdx.x;
    if (t < 64) {
        int hi = ((const int*)eidx)[2 * (t * 25000) + 1];
        unsigned long long b = __ballot(hi != 0);
        if (t == 0) s_is32 = (b != 0ULL) ? 1 : 0;
    }
    __syncthreads();
    const int e = blockIdx.x * 256 + t;        // N_EDGES % 256 == 0, no tail
    int s, d;
    load_edge(eidx, s_is32, e, s, d);
    float4 ss = *(const float4*)(sb16 + (size_t)s * 16);
    float4 sd = *(const float4*)(sb16 + (size_t)d * 16 + 4);
    float4 iv = *(const float4*)(sb16 + (size_t)d * 16 + 8);
    float4 a;
    a.x = __expf(lrelu(ss.x + sd.x)) * iv.x;
    a.y = __expf(lrelu(ss.y + sd.y)) * iv.y;
    a.z = __expf(lrelu(ss.z + sd.z)) * iv.z;
    a.w = __expf(lrelu(ss.w + sd.w)) * iv.w;
    *(float4*)(ebuf + (size_t)e * 4) = a;
}

// ---------------------------------------------------------------------------
extern "C" void kernel_launch(void* const* d_in, const int* in_sizes, int n_in,
                              void* d_out, int out_size, void* d_ws, size_t ws_size,
                              hipStream_t stream) {
    const float* x      = (const float*)d_in[0];
    const void*  eidx   = d_in[1];
    const float* weight = (const float*)d_in[2];
    const float* attn   = (const float*)d_in[3];

    float* out   = (float*)d_out;
    float* out_h = out;                                   // [N_NODES, 128]
    float* ebuf  = out + (size_t)N_NODES * WH_DIM;        // [N_EDGES, 4] alpha

    // workspace layout (64-B aligned); total ~35.6 MB, NO aliasing.
    char* ws = (char*)d_ws;
    int*   win_cnt = (int*)ws;                            // 16 B
    int*   bar     = (int*)(ws + 64);                     // 32 B (3 used)
    int*   bsum2   = (int*)(ws + 128);                    // 196 B (49 used)
    short* bsw_pre = (short*)(ws + 1024);                 // 36,864 B
    int*   noff    = (int*)(ws + 37952);                  // 200,004 B
    int*   win_sd  = (int*)(ws + 238016);                 // 6.56 MB packed
    int*   hist    = (int*)(ws + 6798080);                // 6.4 MB [w][c][bin]
    int*   csr     = (int*)(ws + 13198144);               // 6.4 MB
    __hip_bfloat16* Wh16 = (__hip_bfloat16*)(ws + 19598208);  // 12.8 MB
    float* sb16    = (float*)(ws + 32398272);             // 3.2 MB [n][16]

    k_prep0<<<NB_PREP, 256, 0, stream>>>(weight, attn, bsw_pre, win_cnt, bar);
    k_cvtwh<<<NB_CVT + NB_WH, 256, 0, stream>>>(eidx, x, bsw_pre, win_cnt,
                                                win_sd, Wh16, sb16);
    k_sort<<<NB_SORT, 1024, 0, stream>>>(win_cnt, win_sd, hist, bsum2,
                                         noff, csr, bar);
    k_node<<<N_NODES / 4, 256, 0, stream>>>(noff, csr, sb16, Wh16, out_h);
    k_alpha<<<N_EDGES / 256, 256, 0, stream>>>(eidx, sb16, ebuf);
}

// Round 10
// 250.904 us; speedup vs baseline: 1.1021x; 1.1021x over previous
//
#include <hip/hip_runtime.h>
#include <hip/hip_bf16.h>
#include <math.h>

#define N_NODES 50000
#define N_EDGES 1600000
#define IN_DIM  128
#define OUT_DIM 32
#define N_HEADS 4
#define WH_DIM  (N_HEADS * OUT_DIM)   // 128
#define CAP     128                   // per-node LDS edge cache (max deg ~58)
#define NB_SCAN 196                   // ceil(50000/256)
#define NPASS   4                     // dst-windows
#define WIN     (N_NODES / NPASS)     // 12500
#define NCH2    32                    // chunks per window
#define SEGCAP  410000                // per-window capacity
#define UNROLL  16                    // edges per thread in cvt blocks
#define EPB     (256 * UNROLL)        // 4096 edges per cvt block
#define NB_CVT  391                   // ceil(1600000/4096)
#define NB_WH   782                   // ceil(50000/64)
#define NB_PREP 16
#define SFLAG   (1 << 30)             // bsum published flag

typedef __attribute__((ext_vector_type(8))) short short8;     // 8 bf16
typedef __attribute__((ext_vector_type(4))) float floatx4;    // MFMA acc

__device__ __forceinline__ short f2bf(float v) {
    __hip_bfloat16 b = __float2bfloat16(v);
    return *reinterpret_cast<short*>(&b);
}
__device__ __forceinline__ float lrelu(float v) {
    return v > 0.0f ? v : 0.2f * v;
}

// ---------------------------------------------------------------------------
// edge_index may arrive as int32 or int64 (reference dtype).
// ---------------------------------------------------------------------------
__device__ __forceinline__ void load_edge(const void* eidx, int is32, int e,
                                          int& s, int& d) {
    if (is32) {
        const int2 v = ((const int2*)eidx)[e];
        s = v.x; d = v.y;
    } else {
        const longlong2 v = ((const longlong2*)eidx)[e];
        s = (int)v.x; d = (int)v.y;
    }
}

// ---------------------------------------------------------------------------
// k_prep0 (16 blocks): swizzled bf16 B panel split 16 ways (R8's 1-block
// version serialized 64 strided-load rounds on one CU). Block 0 additionally
// zeroes win_cnt + bsum and computes U + extension cols.
// ---------------------------------------------------------------------------
__global__ __launch_bounds__(256) void k_prep0(
        const float* __restrict__ weight, const float* __restrict__ attn,
        short* __restrict__ bsw_pre, int* __restrict__ win_cnt,
        int* __restrict__ bsum) {
    __shared__ float ubuf[128 * 8];            // 4 KB
    const int t = threadIdx.x;
    const int b = blockIdx.x;
    // ---- main panel slice: 1024 entries per block
    for (int f = b * 1024 + t; f < (b + 1) * 1024; f += 256) {
        int k = f >> 7, c = f & 127;
        float w = weight[(c >> 5) * (IN_DIM * OUT_DIM) + k * OUT_DIM + (c & 31)];
        int kc = k >> 5, quad = (k >> 3) & 3, j = k & 7;
        bsw_pre[((kc * 9 + (c >> 4)) * 64 + quad * 16 + (c & 15)) * 8 + j] =
            f2bf(w);
    }
    if (b != 0) return;
    // ---- block 0: zero counters, U, extension cols
    if (t < NPASS) win_cnt[t] = 0;
    if (t < NB_SCAN) bsum[t] = 0;
    {
        int c = t & 7, k0 = t >> 3;            // k0 in [0,32)
        int h = c & 3;
        const float* ap = attn + h * 64 + (c >> 2) * 32;
        for (int k = k0; k < 128; k += 32) {
            const float* wp = weight + h * (IN_DIM * OUT_DIM) + k * OUT_DIM;
            float u = 0.f;
#pragma unroll
            for (int o = 0; o < 32; o += 4) {
                float4 wv = *(const float4*)(wp + o);
                float4 av = *(const float4*)(ap + o);
                u += wv.x * av.x + wv.y * av.y + wv.z * av.z + wv.w * av.w;
            }
            ubuf[k * 8 + c] = u;
        }
    }
    __syncthreads();
    for (int f = t; f < 128 * 16; f += 256) {
        int k = f >> 4, c = f & 15;
        float w = (c < 8) ? ubuf[k * 8 + c] : 0.f;
        int kc = k >> 5, quad = (k >> 3) & 3, j = k & 7;
        bsw_pre[((kc * 9 + 8) * 64 + quad * 16 + c) * 8 + j] = f2bf(w);
    }
}

// ---------------------------------------------------------------------------
// k_cvtwh: FUSED edge-binning + Wh GEMM (independent work, one launch).
// Blocks [0,NB_CVT): bin edges into 4 dst-window segments, PACKED as
//   p = s | ((d - w*WIN) << 17). Ballot ranks, ONE atomicAdd/window/block.
// Blocks [NB_CVT,..): 64 nodes x 144 cols MFMA GEMM from bsw_pre.
// ---------------------------------------------------------------------------
union CvtWhSmem {
    struct {
        int s_is32;
        int wcnt[NPASS][UNROLL][4];            // [win][iter][wave]
        int pb[NPASS][UNROLL][4];              // block-relative bases
        int bw[NPASS];                         // per-window block base
    } c;
    struct {
        short xsw[4 * 4 * 64 * 8];             // 16 KB [wg][kc][lane][j]
        short bsw[4 * 9 * 64 * 8];             // 36 KB [kc][cg][lane][j]
    } w;
};

__global__ __launch_bounds__(256) void k_cvtwh(
        const void* __restrict__ eidx, const float* __restrict__ x,
        const short* __restrict__ bsw_pre,
        int* __restrict__ win_cnt, int* __restrict__ win_sd,
        __hip_bfloat16* __restrict__ Wh16, float* __restrict__ sb16) {
    __shared__ CvtWhSmem sm;
    const int t = threadIdx.x;

    if (blockIdx.x < NB_CVT) {
        // ================= cvt branch =================
        const int wv = t >> 6, lane = t & 63;
        if (t < 64) {
            int hi = ((const int*)eidx)[2 * (t * 25000) + 1];
            unsigned long long b = __ballot(hi != 0);
            if (t == 0) sm.c.s_is32 = (b != 0ULL) ? 1 : 0;
        }
        __syncthreads();
        const int is32 = sm.c.s_is32;
        const int e0 = blockIdx.x * EPB;
        int sg[UNROLL], dg[UNROLL];
#pragma unroll
        for (int i = 0; i < UNROLL; ++i) {
            const int e = e0 + i * 256 + t;
            int s = 0, d = -1;
            if (e < N_EDGES) load_edge(eidx, is32, e, s, d);
            sg[i] = s; dg[i] = d;
            const int w = (d >= 0) ? (d / WIN) : -1;
            const unsigned long long m0 = __ballot(w == 0);
            const unsigned long long m1 = __ballot(w == 1);
            const unsigned long long m2 = __ballot(w == 2);
            const unsigned long long m3 = __ballot(w == 3);
            if (lane == 0) {
                sm.c.wcnt[0][i][wv] = __popcll(m0);
                sm.c.wcnt[1][i][wv] = __popcll(m1);
                sm.c.wcnt[2][i][wv] = __popcll(m2);
                sm.c.wcnt[3][i][wv] = __popcll(m3);
            }
        }
        __syncthreads();
        if (t < NPASS) {
            int run = 0;
            for (int i = 0; i < UNROLL; ++i)
                for (int v = 0; v < 4; ++v) {
                    sm.c.pb[t][i][v] = run;
                    run += sm.c.wcnt[t][i][v];
                }
            sm.c.bw[t] = atomicAdd(&win_cnt[t], run);
        }
        __syncthreads();
        const unsigned long long mlt = (1ULL << lane) - 1ULL;
#pragma unroll
        for (int i = 0; i < UNROLL; ++i) {
            const int d = dg[i];
            const int w = (d >= 0) ? (d / WIN) : -1;
            const unsigned long long m0 = __ballot(w == 0);
            const unsigned long long m1 = __ballot(w == 1);
            const unsigned long long m2 = __ballot(w == 2);
            const unsigned long long m3 = __ballot(w == 3);
            if (w >= 0) {
                const unsigned long long mw = (w == 0) ? m0 : (w == 1) ? m1
                                            : (w == 2) ? m2 : m3;
                const int rank = __popcll(mw & mlt);
                const int p = sm.c.bw[w] + sm.c.pb[w][i][wv] + rank;
                if (p < SEGCAP)
                    win_sd[w * SEGCAP + p] = sg[i] | ((d - w * WIN) << 17);
            }
        }
    } else {
        // ================= wh branch =================
        const int nb = (blockIdx.x - NB_CVT) * 64;
        for (int f = t; f < 4 * 9 * 64; f += 256)
            *(short8*)&sm.w.bsw[f * 8] = *(const short8*)&bsw_pre[f * 8];
        for (int f = t; f < 64 * 32; f += 256) {
            int n = f >> 5, k = (f & 31) * 4;
            int ng = nb + n; if (ng > N_NODES - 1) ng = N_NODES - 1;
            float4 v = *(const float4*)(x + (size_t)ng * IN_DIM + k);
            int wg = n >> 4, m = n & 15, kc = k >> 5, quad = (k >> 3) & 3,
                j = k & 7;
            short4 sv = make_short4(f2bf(v.x), f2bf(v.y), f2bf(v.z), f2bf(v.w));
            *(short4*)&sm.w.xsw[(((wg * 4 + kc) * 64) + quad * 16 + m) * 8 + j]
                = sv;
        }
        __syncthreads();
        const int wg = t >> 6, lane = t & 63;
        floatx4 acc[9];
#pragma unroll
        for (int i = 0; i < 9; ++i) acc[i] = (floatx4){0.f, 0.f, 0.f, 0.f};
#pragma unroll
        for (int kc = 0; kc < 4; ++kc) {
            short8 a = *(short8*)&sm.w.xsw[((wg * 4 + kc) * 64 + lane) * 8];
#pragma unroll
            for (int cg = 0; cg < 9; ++cg) {
                short8 b = *(short8*)&sm.w.bsw[((kc * 9 + cg) * 64 + lane) * 8];
                acc[cg] = __builtin_amdgcn_mfma_f32_16x16x32_bf16(a, b, acc[cg],
                                                                  0, 0, 0);
            }
        }
        const int col = lane & 15, quad = lane >> 4;
#pragma unroll
        for (int r = 0; r < 4; ++r) {
            int n = nb + wg * 16 + quad * 4 + r;
            if (n >= N_NODES) continue;
#pragma unroll
            for (int cg = 0; cg < 8; ++cg)
                Wh16[(size_t)n * WH_DIM + cg * 16 + col] =
                    __float2bfloat16(acc[cg][r]);
            if (col < 8) sb16[(size_t)n * 16 + col] = acc[8][r];
        }
    }
}

// ---------------------------------------------------------------------------
// k_hist: (chunk, window) blocks; reads only its window's packed segment.
// d is window-relative in bits [17,31). LDS histogram, no global atomics.
// ---------------------------------------------------------------------------
__global__ __launch_bounds__(1024) void k_hist(
        const int* __restrict__ win_cnt, const int* __restrict__ win_sd,
        int* __restrict__ hist) {
    __shared__ int hbin[WIN];                  // 50 KB
    const int c = blockIdx.x, w = blockIdx.y;
    for (int i = threadIdx.x; i < WIN; i += 1024) hbin[i] = 0;
    __syncthreads();
    const int cw = win_cnt[w];
    const int ce = (cw + NCH2 - 1) / NCH2;
    const int lo = c * ce;
    const int hi = min(lo + ce, cw);
    for (int i = lo + threadIdx.x; i < hi; i += 1024) {
        unsigned u = ((unsigned)win_sd[w * SEGCAP + i]) >> 17;
        if (u < WIN) atomicAdd(&hbin[u], 1);
    }
    __syncthreads();
    for (int i = threadIdx.x; i < WIN; i += 1024)
        hist[(w * NCH2 + c) * WIN + i] = hbin[i];
}

// ---------------------------------------------------------------------------
// k_scanbase: FUSED scan1+scan2+base. Per-node totals + block-local LDS
// exclusive scan; publish block sum (SFLAG) via atomicExch; poll all 196
// (publish unconditional before any poll -> no circular wait); emit noff[]
// and convert hist[w][c][bin] in place to running scatter bases.
// ---------------------------------------------------------------------------
__global__ __launch_bounds__(256) void k_scanbase(
        int* __restrict__ bsum, int* __restrict__ hist,
        int* __restrict__ noff) {
    __shared__ int sh[256];
    const int t = threadIdx.x;
    const int b = blockIdx.x;
    const int i = b * 256 + t;
    int v = 0;
    if (i < N_NODES) {
        const int w = i / WIN, bin = i % WIN;
        for (int c = 0; c < NCH2; ++c) v += hist[(w * NCH2 + c) * WIN + bin];
    }
    sh[t] = v;
    __syncthreads();
    for (int d = 1; d < 256; d <<= 1) {
        int u = (t >= d) ? sh[t - d] : 0;
        __syncthreads();
        sh[t] += u;
        __syncthreads();
    }
    const int myex = sh[t] - v;                // block-local exclusive prefix
    if (t == 255) atomicExch(&bsum[b], sh[255] | SFLAG);
    __syncthreads();
    int bvv = 0;
    if (t < NB_SCAN) {
        int xx;
        do { xx = atomicAdd(&bsum[t], 0); } while (!(xx & SFLAG));
        bvv = xx & ~SFLAG;
    }
    sh[t] = bvv;
    __syncthreads();
    for (int d = 1; d < 256; d <<= 1) {
        int u = (t >= d) ? sh[t - d] : 0;
        __syncthreads();
        sh[t] += u;
        __syncthreads();
    }
    const int exb = (b == 0) ? 0 : sh[b - 1];  // exclusive block prefix
    if (b == 0 && t == 0) noff[N_NODES] = N_EDGES;
    if (i >= N_NODES) return;
    int run = myex + exb;
    noff[i] = run;
    const int w = i / WIN, bin = i % WIN;
    for (int c = 0; c < NCH2; ++c) {
        const int idx = (w * NCH2 + c) * WIN + bin;
        int t0 = hist[idx];
        hist[idx] = run;
        run += t0;
    }
}

// ---------------------------------------------------------------------------
// k_scatter: (chunk, window) blocks; positions via LDS atomics on bases.
// Reads packed segments; window csr region ~1.6 MB L2-resident.
// ---------------------------------------------------------------------------
__global__ __launch_bounds__(1024) void k_scatter(
        const int* __restrict__ win_cnt, const int* __restrict__ win_sd,
        const int* __restrict__ hist, int* __restrict__ csr) {
    __shared__ int pos[WIN];                   // 50 KB
    const int c = blockIdx.x, w = blockIdx.y;
    for (int i = threadIdx.x; i < WIN; i += 1024)
        pos[i] = hist[(w * NCH2 + c) * WIN + i];
    __syncthreads();
    const int cw = win_cnt[w];
    const int ce = (cw + NCH2 - 1) / NCH2;
    const int lo = c * ce;
    const int hi = min(lo + ce, cw);
    for (int i = lo + threadIdx.x; i < hi; i += 1024) {
        const int pk = win_sd[w * SEGCAP + i];
        const int s = pk & 0x1FFFF;
        const unsigned u = ((unsigned)pk) >> 17;
        if (u < WIN) {
            int p = atomicAdd(&pos[u], 1);
            csr[p] = s;
        }
    }
}

// ---------------------------------------------------------------------------
// One wave per dst node. No max pass (softmax shift-invariant; |e| small).
// sb16 row: [0..3]=s_src, [4..7]=s_dst, [8..11]=inv (written here), 64 B.
// Phase D: esl = t>>4 picks 1 of 4 edges, dsl = t&15 picks an 8-dim slice;
// 16-edge unroll -> 4 independent gathers in flight per wave.
// ---------------------------------------------------------------------------
__global__ __launch_bounds__(256) void k_node(
        const int* __restrict__ noff,
        const int* __restrict__ csr, float* __restrict__ sb16,
        const __hip_bfloat16* __restrict__ Wh16,
        float* __restrict__ out_h) {
    __shared__ int    sbuf[4][CAP];
    __shared__ float4 e4b[4][CAP];                      // exp(e) values
    const int wv = threadIdx.x >> 6;
    const int t  = threadIdx.x & 63;
    const int n  = blockIdx.x * 4 + wv;
    const int beg = noff[n];
    const int end = noff[n + 1];
    const int deg = end - beg;

    const float4 sd = *(const float4*)(sb16 + (size_t)n * 16 + 4);

    // Phase A: ex = exp(lrelu(s_src[src] + s_dst[n])); cache; running sum
    float4 sum = {0.f, 0.f, 0.f, 0.f};
    for (int l = t; l < deg; l += 64) {
        int s = csr[beg + l];
        float4 ss = *(const float4*)(sb16 + (size_t)s * 16);
        float4 ex;
        ex.x = __expf(lrelu(ss.x + sd.x));
        ex.y = __expf(lrelu(ss.y + sd.y));
        ex.z = __expf(lrelu(ss.z + sd.z));
        ex.w = __expf(lrelu(ss.w + sd.w));
        if (l < CAP) { sbuf[wv][l] = s; e4b[wv][l] = ex; }
        sum.x += ex.x; sum.y += ex.y; sum.z += ex.z; sum.w += ex.w;
    }
#pragma unroll
    for (int o = 32; o; o >>= 1) {
        sum.x += __shfl_xor(sum.x, o);
        sum.y += __shfl_xor(sum.y, o);
        sum.z += __shfl_xor(sum.z, o);
        sum.w += __shfl_xor(sum.w, o);
    }
    float4 inv;
    inv.x = 1.0f / (sum.x + 1e-9f); inv.y = 1.0f / (sum.y + 1e-9f);
    inv.z = 1.0f / (sum.z + 1e-9f); inv.w = 1.0f / (sum.w + 1e-9f);
    if (t == 0) *(float4*)(sb16 + (size_t)n * 16 + 8) = inv;

    // Phase D
    const int esl = t >> 4;
    const int dsl = t & 15;
    const int h   = dsl >> 2;
    const float invh = (h == 0) ? inv.x : (h == 1) ? inv.y
                     : (h == 2) ? inv.z : inv.w;
    const float sdh  = (h == 0) ? sd.x : (h == 1) ? sd.y
                     : (h == 2) ? sd.z : sd.w;
    float acc0 = 0.f, acc1 = 0.f, acc2 = 0.f, acc3 = 0.f;
    float acc4 = 0.f, acc5 = 0.f, acc6 = 0.f, acc7 = 0.f;
    if (deg <= CAP) {
        const int sPad = sbuf[wv][0];
        for (int jb = 0; jb < deg; jb += 16) {
            int   sg[4];
            float ag[4];
#pragma unroll
            for (int g = 0; g < 4; ++g) {
                const int idx = jb + g * 4 + esl;
                sg[g] = sPad;
                ag[g] = 0.f;
                if (idx < deg) {
                    sg[g] = sbuf[wv][idx];
                    ag[g] = ((const float*)&e4b[wv][idx])[h];
                }
            }
            uint4 w0 = *(const uint4*)(Wh16 + (size_t)sg[0] * WH_DIM + dsl * 8);
            uint4 w1 = *(const uint4*)(Wh16 + (size_t)sg[1] * WH_DIM + dsl * 8);
            uint4 w2 = *(const uint4*)(Wh16 + (size_t)sg[2] * WH_DIM + dsl * 8);
            uint4 w3 = *(const uint4*)(Wh16 + (size_t)sg[3] * WH_DIM + dsl * 8);
#define ACC8(W, A)                                                            \
            acc0 += (A) * __uint_as_float((W).x << 16);                       \
            acc1 += (A) * __uint_as_float((W).x & 0xffff0000u);               \
            acc2 += (A) * __uint_as_float((W).y << 16);                       \
            acc3 += (A) * __uint_as_float((W).y & 0xffff0000u);               \
            acc4 += (A) * __uint_as_float((W).z << 16);                       \
            acc5 += (A) * __uint_as_float((W).z & 0xffff0000u);               \
            acc6 += (A) * __uint_as_float((W).w << 16);                       \
            acc7 += (A) * __uint_as_float((W).w & 0xffff0000u)
            ACC8(w0, ag[0]);
            ACC8(w1, ag[1]);
            ACC8(w2, ag[2]);
            ACC8(w3, ag[3]);
#undef ACC8
        }
    } else {
        for (int jb = 0; jb < deg; jb += 4) {
            const int idx = jb + esl;
            float a = 0.f;
            int s = sbuf[wv][0];
            if (idx < deg) {
                if (idx < CAP) {
                    s = sbuf[wv][idx];
                    a = ((const float*)&e4b[wv][idx])[h];
                } else {
                    s = csr[beg + idx];
                    a = __expf(lrelu(sb16[(size_t)s * 16 + h] + sdh));
                }
            }
            const uint4 w = *(const uint4*)(Wh16 + (size_t)s * WH_DIM + dsl * 8);
            acc0 += a * __uint_as_float(w.x << 16);
            acc1 += a * __uint_as_float(w.x & 0xffff0000u);
            acc2 += a * __uint_as_float(w.y << 16);
            acc3 += a * __uint_as_float(w.y & 0xffff0000u);
            acc4 += a * __uint_as_float(w.z << 16);
            acc5 += a * __uint_as_float(w.z & 0xffff0000u);
            acc6 += a * __uint_as_float(w.w << 16);
            acc7 += a * __uint_as_float(w.w & 0xffff0000u);
        }
    }
    acc0 += __shfl_xor(acc0, 16); acc0 += __shfl_xor(acc0, 32);
    acc1 += __shfl_xor(acc1, 16); acc1 += __shfl_xor(acc1, 32);
    acc2 += __shfl_xor(acc2, 16); acc2 += __shfl_xor(acc2, 32);
    acc3 += __shfl_xor(acc3, 16); acc3 += __shfl_xor(acc3, 32);
    acc4 += __shfl_xor(acc4, 16); acc4 += __shfl_xor(acc4, 32);
    acc5 += __shfl_xor(acc5, 16); acc5 += __shfl_xor(acc5, 32);
    acc6 += __shfl_xor(acc6, 16); acc6 += __shfl_xor(acc6, 32);
    acc7 += __shfl_xor(acc7, 16); acc7 += __shfl_xor(acc7, 32);
    if (t < 16) {
        float* op = out_h + (size_t)n * WH_DIM + dsl * 8;
        float4 o0 = {acc0 * invh, acc1 * invh, acc2 * invh, acc3 * invh};
        float4 o1 = {acc4 * invh, acc5 * invh, acc6 * invh, acc7 * invh};
        *(float4*)op = o0;
        *(float4*)(op + 4) = o1;
    }
}

// ---------------------------------------------------------------------------
// Edge-parallel alpha: reads eidx directly (L3-resident); dst-side gather
// (sd+inv) hits one 64 B line per edge; coalesced float4 write.
// ---------------------------------------------------------------------------
__global__ __launch_bounds__(256) void k_alpha(
        const void* __restrict__ eidx,
        const float* __restrict__ sb16, float* __restrict__ ebuf) {
    __shared__ int s_is32;
    const int t = threadIdx.x;
    if (t < 64) {
        int hi = ((const int*)eidx)[2 * (t * 25000) + 1];
        unsigned long long b = __ballot(hi != 0);
        if (t == 0) s_is32 = (b != 0ULL) ? 1 : 0;
    }
    __syncthreads();
    const int e = blockIdx.x * 256 + t;        // N_EDGES % 256 == 0, no tail
    int s, d;
    load_edge(eidx, s_is32, e, s, d);
    float4 ss = *(const float4*)(sb16 + (size_t)s * 16);
    float4 sd = *(const float4*)(sb16 + (size_t)d * 16 + 4);
    float4 iv = *(const float4*)(sb16 + (size_t)d * 16 + 8);
    float4 a;
    a.x = __expf(lrelu(ss.x + sd.x)) * iv.x;
    a.y = __expf(lrelu(ss.y + sd.y)) * iv.y;
    a.z = __expf(lrelu(ss.z + sd.z)) * iv.z;
    a.w = __expf(lrelu(ss.w + sd.w)) * iv.w;
    *(float4*)(ebuf + (size_t)e * 4) = a;
}

// ---------------------------------------------------------------------------
extern "C" void kernel_launch(void* const* d_in, const int* in_sizes, int n_in,
                              void* d_out, int out_size, void* d_ws, size_t ws_size,
                              hipStream_t stream) {
    const float* x      = (const float*)d_in[0];
    const void*  eidx   = d_in[1];
    const float* weight = (const float*)d_in[2];
    const float* attn   = (const float*)d_in[3];

    float* out   = (float*)d_out;
    float* out_h = out;                                   // [N_NODES, 128]
    float* ebuf  = out + (size_t)N_NODES * WH_DIM;        // [N_EDGES, 4] alpha

    // workspace layout (64-B aligned); total ~35.6 MB, NO aliasing.
    char* ws = (char*)d_ws;
    int*   win_cnt = (int*)ws;                            // 16 B
    int*   bsum    = (int*)(ws + 64);                     // 784 B
    short* bsw_pre = (short*)(ws + 1024);                 // 36,864 B
    int*   noff    = (int*)(ws + 37952);                  // 200,004 B
    int*   win_sd  = (int*)(ws + 238016);                 // 6.56 MB packed
    int*   hist    = (int*)(ws + 6798080);                // 6.4 MB [w][c][bin]
    int*   csr     = (int*)(ws + 13198144);               // 6.4 MB
    __hip_bfloat16* Wh16 = (__hip_bfloat16*)(ws + 19598208);  // 12.8 MB
    float* sb16    = (float*)(ws + 32398272);             // 3.2 MB [n][16]

    k_prep0<<<NB_PREP, 256, 0, stream>>>(weight, attn, bsw_pre, win_cnt, bsum);
    k_cvtwh<<<NB_CVT + NB_WH, 256, 0, stream>>>(eidx, x, bsw_pre, win_cnt,
                                                win_sd, Wh16, sb16);
    dim3 hg(NCH2, NPASS);
    k_hist<<<hg, 1024, 0, stream>>>(win_cnt, win_sd, hist);
    k_scanbase<<<NB_SCAN, 256, 0, stream>>>(bsum, hist, noff);
    k_scatter<<<hg, 1024, 0, stream>>>(win_cnt, win_sd, hist, csr);
    k_node<<<N_NODES / 4, 256, 0, stream>>>(noff, csr, sb16, Wh16, out_h);
    k_alpha<<<N_EDGES / 256, 256, 0, stream>>>(eidx, sb16, ebuf);
}